// Round 14
// baseline (841.211 us; speedup 1.0000x reference)
//
#include <hip/hip_runtime.h>
#include <math.h>

#define N 1024
#define F 4096
#define NLAYERS 24
#define VOCAB 50277
#define GRID 256
#define BLOCK 512   // wave0 = producer/sweeper, waves 1-7 = GEMV workers

// ws floats: r2buf[N]@0; sxacc[2][4][N]@N; facc[2][4][N]@N+8192
#define SXACC_OFF N
#define FACC_OFF (N + 8192)
#define BAR_OFF_BYTES 69632
#define LINE 16
#define BAR_DWORDS (256 * LINE)
#define WS_CLEAR_BYTES (BAR_OFF_BYTES + BAR_DWORDS * 4)

__device__ __forceinline__ float dot4(float4 a, float4 b) {
  return fmaf(a.x, b.x, fmaf(a.y, b.y, fmaf(a.z, b.z, a.w * b.w)));
}
__device__ __forceinline__ float wred(float v) {
#pragma unroll
  for (int o = 32; o > 0; o >>= 1) v += __shfl_down(v, o, 64);
  return v;
}
__device__ __forceinline__ float bfly(float v) {
#pragma unroll
  for (int o = 1; o < 64; o <<= 1) v += __shfl_xor(v, o, 64);
  return v;
}
__device__ __forceinline__ float sigmoidf(float x) { return 1.f / (1.f + expf(-x)); }

__device__ __forceinline__ float2 ld_c2(const float* p) {
  unsigned long long u = __hip_atomic_load((const unsigned long long*)p,
                                           __ATOMIC_RELAXED, __HIP_MEMORY_SCOPE_AGENT);
  float2 f;
  f.x = __uint_as_float((unsigned)u);
  f.y = __uint_as_float((unsigned)(u >> 32));
  return f;
}
__device__ __forceinline__ void st_c(float* p, float v) {
  __hip_atomic_store(p, v, __ATOMIC_RELAXED, __HIP_MEMORY_SCOPE_AGENT);
}
__device__ __forceinline__ unsigned ld_cu(const unsigned* p) {
  return __hip_atomic_load(p, __ATOMIC_RELAXED, __HIP_MEMORY_SCOPE_AGENT);
}
__device__ __forceinline__ void st_cu(unsigned* p, unsigned v) {
  __hip_atomic_store(p, v, __ATOMIC_RELAXED, __HIP_MEMORY_SCOPE_AGENT);
}

__device__ __forceinline__ void lbar() {
  asm volatile("s_waitcnt lgkmcnt(0)" ::: "memory");
  __builtin_amdgcn_s_barrier();
}

// arrive: full drain, block barrier, wave0-lane0 publishes flag
__device__ __forceinline__ void gbar_arrive(unsigned* arr, unsigned gen, int blk,
                                            int tid) {
  asm volatile("s_waitcnt vmcnt(0) lgkmcnt(0)" ::: "memory");
  __builtin_amdgcn_s_barrier();
  if (tid == 0) st_cu(arr + blk * LINE, gen);
}
// wave0 (vmem-clean): sweep all 256 flags
__device__ __forceinline__ void sweep(const unsigned* arr, unsigned gen, int lane) {
  for (;;) {
    bool ok = true;
#pragma unroll
    for (int i = 0; i < 4; ++i)
      ok &= (ld_cu(arr + (lane * 4 + i) * LINE) >= gen);
    if (__all(ok)) break;
    __builtin_amdgcn_s_sleep(1);
  }
  asm volatile("" ::: "memory");
}
__device__ __forceinline__ void set_gen(unsigned* sg, unsigned gen) {
  asm volatile("s_waitcnt lgkmcnt(0)" ::: "memory");
  __hip_atomic_store(sg, gen, __ATOMIC_RELEASE, __HIP_MEMORY_SCOPE_WORKGROUP);
}
__device__ __forceinline__ void wait_gen(const unsigned* sg, unsigned gen) {
  while (__hip_atomic_load(sg, __ATOMIC_ACQUIRE, __HIP_MEMORY_SCOPE_WORKGROUP) < gen)
    __builtin_amdgcn_s_sleep(1);
  asm volatile("" ::: "memory");
}

// redundant-per-wave LayerNorm of 16 lane-columns in q[4] (full N vector/wave)
__device__ __forceinline__ void ln16(float4* q, const float* __restrict__ w,
                                     const float* __restrict__ b, int lane) {
  float s = 0.f, sq = 0.f;
#pragma unroll
  for (int k = 0; k < 4; ++k) {
    s += q[k].x + q[k].y + q[k].z + q[k].w;
    sq += dot4(q[k], q[k]);
  }
  s = bfly(s);
  sq = bfly(sq);
  float mu = s * (1.f / N);
  float rstd = rsqrtf(sq * (1.f / N) - mu * mu + 1e-5f);
#pragma unroll
  for (int k = 0; k < 4; ++k) {
    float4 w4 = ((const float4*)w)[(k << 6) + lane];
    float4 b4 = ((const float4*)b)[(k << 6) + lane];
    q[k].x = (q[k].x - mu) * rstd * w4.x + b4.x;
    q[k].y = (q[k].y - mu) * rstd * w4.y + b4.y;
    q[k].z = (q[k].z - mu) * rstd * w4.z + b4.z;
    q[k].w = (q[k].w - mu) * rstd * w4.w + b4.w;
  }
}

__device__ __forceinline__ float4 mix4(float4 a, float4 s, float4 m) {
  float4 r;
  r.x = a.x * m.x + s.x * (1.f - m.x);
  r.y = a.y * m.y + s.y * (1.f - m.y);
  r.z = a.z * m.z + s.z * (1.f - m.z);
  r.w = a.w * m.w + s.w * (1.f - m.w);
  return r;
}

__device__ __forceinline__ void wkv1(float k, float v, float r, float aa, float bb,
                                     float pp, float tf, float td, float& rab,
                                     float& naa, float& nbb, float& npp) {
  float ww = tf + k;
  float q = fmaxf(pp, ww);
  float e1 = expf(pp - q);
  float e2 = expf(ww - q);
  float a = e1 * aa + e2 * v;
  float b = e1 * bb + e2;
  rab = r * a / b;
  float ww2 = pp + td;
  float q2 = fmaxf(ww2, k);
  float f1 = expf(ww2 - q2);
  float f2 = expf(k - q2);
  naa = f1 * aa + f2 * v;
  nbb = f1 * bb + f2;
  npp = q2;
}

__global__ __launch_bounds__(BLOCK, 1) void k_rwkv(
    const int* __restrict__ ctx, const float* __restrict__ state,
    const float* __restrict__ emb, const float* __restrict__ ln0w,
    const float* __restrict__ ln0b, const float* __restrict__ ln1w,
    const float* __restrict__ ln1b, const float* __restrict__ amk,
    const float* __restrict__ amv, const float* __restrict__ amr,
    const float* __restrict__ tf, const float* __restrict__ td,
    const float* __restrict__ kw, const float* __restrict__ vw,
    const float* __restrict__ rw, const float* __restrict__ ow,
    const float* __restrict__ ln2w, const float* __restrict__ ln2b,
    const float* __restrict__ fmk, const float* __restrict__ fmr,
    const float* __restrict__ fkw, const float* __restrict__ fvw,
    const float* __restrict__ frw, const float* __restrict__ lnoutw,
    const float* __restrict__ lnoutb, const float* __restrict__ head,
    float* __restrict__ out, float* __restrict__ ws, unsigned* __restrict__ bar) {
  __shared__ __align__(16) float s_vx[N];       // layer input x (wave0-produced)
  __shared__ __align__(16) float s_sx[N];       // sx (wave0-produced)
  __shared__ __align__(16) float s_abv[6 * N];  // ln1w,ln1b,amk,amv,amr,s1
  __shared__ __align__(16) float s_cbv[5 * N];  // ln2w,ln2b,fmk,fmr,s0
  __shared__ __align__(16) float s_ex[16];      // k[4],v[4],r[4],rab[4]
  __shared__ __align__(16) float s_kk[16];
  __shared__ unsigned s_flag;

  const int tid = threadIdx.x;
  const int lane = tid & 63;
  const int wid = tid >> 6;
  const bool work = (wid > 0);
  const int blk = blockIdx.x;
  const size_t nn = (size_t)N * N;

  if (tid == 0) s_flag = 0;
  __syncthreads();

  float* logits = out;
  float* st_out = out + VOCAB;
  float* r2buf = ws;
  float* sxacc = ws + SXACC_OFF;  // [2][4][N]
  float* facc = ws + FACC_OFF;    // [2][4][N]
  unsigned bgen = 0, fgen = 0;

  // XCD-team col ownership (4 blocks share a 16-col panel)
  const int xcd = blk & 7, sgrp = blk >> 3;
  const int jm = sgrp & 3, gg = sgrp >> 2;
  const int c0 = (((xcd + (gg << 3)) << 4) + (jm << 2));

  const int wl = (wid - 1) * 64 + lane;       // worker flat lane [0,448)
  // AB rows: 0-3 kw, 4-7 vw, 8-11 rw
  const int rI = wid - 1;                     // 0..6
  const int rJ = wid + 6;                     // 7..11 valid
  const bool hasJ = (wid >= 1 && wid <= 5);
  // C rows: 0-15 fkw, 16-19 frw
  const int iA = (wid <= 6) ? 3 * (wid - 1) : 18;
  const int iB = iA + 1;
  const int iC = iA + 2;
  const bool hasC = (wid >= 1 && wid <= 6);
  // panel rows over 448 workers: wl, wl+448, wl+896(wid 1-2)
  const bool has3 = (wid == 1 || wid == 2);
  const int rv0 = work ? ((wl + (blk << 2)) & (N - 1)) : 0;
  const int rv1 = work ? ((wl + 448 + (blk << 2)) & (N - 1)) : 0;
  const int rv2 = work ? ((wl + 896 + (blk << 2)) & (N - 1)) : 0;

  float4 paI[4], paJ[4], powr0, powr1, powr2;
  float4 pkA[4], pkB[4], pkC[4], pf0[4], pf1[4], pf2[4];
  float kaa = 0.f, kbb = 0.f, kpp = 0.f, ktf = 0.f, ktd = 0.f;

  auto abaddr = [&](int u, int lc) -> const float* {
    int vec = u >> 8, off = (u & 255) << 2;
    const float* s = (vec == 0)   ? ln1w + lc * N
                     : (vec == 1) ? ln1b + lc * N
                     : (vec == 2) ? amk + lc * N
                     : (vec == 3) ? amv + lc * N
                     : (vec == 4) ? amr + lc * N
                                  : state + (size_t)lc * 5 * N + N;
    return s + off;
  };
  auto cbaddr = [&](int u, int lc) -> const float* {
    int vec = u >> 8, off = (u & 255) << 2;
    const float* s = (vec == 0)   ? ln2w + lc * N
                     : (vec == 1) ? ln2b + lc * N
                     : (vec == 2) ? fmk + lc * N
                     : (vec == 3) ? fmr + lc * N
                                  : state + (size_t)lc * 5 * N;
    return s + off;
  };
  auto parow = [&](int r, int lc) -> const float* {
    int m = r >> 2;
    const float* base = (m == 0) ? kw : (m == 1) ? vw : rw;
    return base + (size_t)lc * nn + (size_t)(c0 + (r & 3)) * N;
  };
  auto pcrow = [&](int i, int lc) -> const float* {
    return (i < 16) ? fkw + (size_t)lc * F * N + (size_t)((blk << 4) + i) * N
                    : frw + (size_t)lc * nn + (size_t)((blk << 2) + (i - 16)) * N;
  };
  auto pfA = [&](int lc) {
    const float* WI = parow(rI, lc);
#pragma unroll
    for (int k = 0; k < 4; ++k) paI[k] = ((const float4*)WI)[(k << 6) + lane];
    if (hasJ) {
      const float* WJ = parow(rJ, lc);
#pragma unroll
      for (int k = 0; k < 4; ++k) paJ[k] = ((const float4*)WJ)[(k << 6) + lane];
    }
    const float* owl = ow + (size_t)lc * nn;
    powr0 = *(const float4*)(owl + (size_t)rv0 * N + c0);
    powr1 = *(const float4*)(owl + (size_t)rv1 * N + c0);
    if (has3) powr2 = *(const float4*)(owl + (size_t)rv2 * N + c0);
  };
  auto pfC = [&](int lc) {
    const float* WA = pcrow(iA, lc);
#pragma unroll
    for (int k = 0; k < 4; ++k) pkA[k] = ((const float4*)WA)[(k << 6) + lane];
    const float* WB = pcrow(iB, lc);
#pragma unroll
    for (int k = 0; k < 4; ++k) pkB[k] = ((const float4*)WB)[(k << 6) + lane];
    if (hasC) {
      const float* WC = pcrow(iC, lc);
#pragma unroll
      for (int k = 0; k < 4; ++k) pkC[k] = ((const float4*)WC)[(k << 6) + lane];
    }
    const float* fvb = fvw + (size_t)lc * N * F + (blk << 4);
#pragma unroll
    for (int i = 0; i < 4; ++i) pf0[i] = ((const float4*)(fvb + (size_t)rv0 * F))[i];
#pragma unroll
    for (int i = 0; i < 4; ++i) pf1[i] = ((const float4*)(fvb + (size_t)rv1 * F))[i];
    if (has3) {
#pragma unroll
      for (int i = 0; i < 4; ++i) pf2[i] = ((const float4*)(fvb + (size_t)rv2 * F))[i];
    }
  };

  // ================= pre-loop: window-X(0) =================
  ++fgen;
  if (work) {
    // stage ABvec(0) into LDS
    float4 a0 = *(const float4*)abaddr(wl, 0);
    float4 a1 = *(const float4*)abaddr(wl + 448, 0);
    float4 a2 = *(const float4*)abaddr(wl + 896, 0);
    float4 a3;
    if (wl < 192) a3 = *(const float4*)abaddr(wl + 1344, 0);
    pfA(0);
    ((float4*)s_abv)[wl] = a0;
    ((float4*)s_abv)[wl + 448] = a1;
    ((float4*)s_abv)[wl + 896] = a2;
    if (wl < 192) ((float4*)s_abv)[wl + 1344] = a3;
    wait_gen(&s_flag, fgen);
  } else {
    // x0 = LN0(0.2*(4*emb[t1]+emb[t0])) — wave0 alone, 16 elements/lane
    int t1 = ctx[1], t0c = ctx[0];
    const float2* e1p = (const float2*)(emb + (size_t)t1 * N);
    const float2* e0p = (const float2*)(emb + (size_t)t0c * N);
    float2 xv[8];
#pragma unroll
    for (int j = 0; j < 8; ++j) {
      float2 a = e1p[lane * 8 + j], b = e0p[lane * 8 + j];
      xv[j].x = (a.x * 4.f + b.x) * 0.2f;
      xv[j].y = (a.y * 4.f + b.y) * 0.2f;
    }
    float s = 0.f, sq = 0.f;
#pragma unroll
    for (int j = 0; j < 8; ++j) { s += xv[j].x + xv[j].y; sq += xv[j].x * xv[j].x + xv[j].y * xv[j].y; }
    s = bfly(s); sq = bfly(sq);
    float mu = s * (1.f / N);
    float rs = rsqrtf(sq * (1.f / N) - mu * mu + 1e-5f);
#pragma unroll
    for (int j = 0; j < 8; ++j) {
      float2 w2 = ((const float2*)ln0w)[lane * 8 + j];
      float2 b2 = ((const float2*)ln0b)[lane * 8 + j];
      float2 o;
      o.x = (xv[j].x - mu) * rs * w2.x + b2.x;
      o.y = (xv[j].y - mu) * rs * w2.y + b2.y;
      ((float2*)s_vx)[lane * 8 + j] = o;
    }
    set_gen(&s_flag, fgen);
    if (lane < 4) {
      int ii = c0 + lane;
      kaa = state[2 * N + ii];
      kbb = state[3 * N + ii];
      kpp = state[4 * N + ii];
      ktf = tf[ii];
      ktd = td[ii];
    }
  }
  lbar();  // s_abv visible to all

  for (int l = 0; l < NLAYERS; ++l) {
    const int p = l & 1;
    float* sto = st_out + (size_t)l * 5 * N;

    // ================= AB body =================
    float4 cv0, cv1, cv2;
    if (work) {
      // issue C(l) vector loads early (land during dots, written at stage end)
      cv0 = *(const float4*)cbaddr(wl, l);
      cv1 = *(const float4*)cbaddr(wl + 448, l);
      if (wl < 384) cv2 = *(const float4*)cbaddr(wl + 896, l);
      float4 xl[4];
#pragma unroll
      for (int k = 0; k < 4; ++k) xl[k] = ((const float4*)s_vx)[(k << 6) + lane];
      ln16(xl, s_abv, s_abv + N, lane);
      if (blk == 4 && wid == 1) {
#pragma unroll
        for (int k = 0; k < 4; ++k) ((float4*)(sto + N))[(k << 6) + lane] = xl[k];
      }
      float4 mk4[4], mv4[4], mr4[4];
#pragma unroll
      for (int k = 0; k < 4; ++k) {
        float4 s1 = ((const float4*)(s_abv + 5 * N))[(k << 6) + lane];
        mk4[k] = mix4(xl[k], s1, ((const float4*)(s_abv + 2 * N))[(k << 6) + lane]);
        mv4[k] = mix4(xl[k], s1, ((const float4*)(s_abv + 3 * N))[(k << 6) + lane]);
        mr4[k] = mix4(xl[k], s1, ((const float4*)(s_abv + 4 * N))[(k << 6) + lane]);
      }
      int mI = rI >> 2;
      float dI = 0.f;
#pragma unroll
      for (int k = 0; k < 4; ++k) {
        float4 mm = (mI == 0) ? mk4[k] : ((mI == 1) ? mv4[k] : mr4[k]);
        dI += dot4(paI[k], mm);
      }
      dI = wred(dI);
      if (lane == 0) s_ex[rI] = (rI >= 8) ? sigmoidf(dI) : dI;
      if (hasJ) {
        int mJ = rJ >> 2;
        float dJ = 0.f;
#pragma unroll
        for (int k = 0; k < 4; ++k) {
          float4 mm = (mJ == 0) ? mk4[k] : ((mJ == 1) ? mv4[k] : mr4[k]);
          dJ += dot4(paJ[k], mm);
        }
        dJ = wred(dJ);
        if (lane == 0) s_ex[rJ] = (rJ >= 8) ? sigmoidf(dJ) : dJ;
      }
    }
    lbar();
    if (!work && lane < 4) {
      float rab, naa, nbb, npp;
      wkv1(s_ex[lane], s_ex[4 + lane], s_ex[8 + lane], kaa, kbb, kpp, ktf, ktd,
           rab, naa, nbb, npp);
      int ii = c0 + lane;
      sto[2 * N + ii] = naa;
      sto[3 * N + ii] = nbb;
      sto[4 * N + ii] = npp;
      s_ex[12 + lane] = rab;
    }
    lbar();
    if (work) {
      float4 rab4 = *((const float4*)(s_ex + 12));
      float* sxa = sxacc + p * 4096 + (blk & 3) * N;
      unsafeAtomicAdd(sxa + rv0, dot4(powr0, rab4));
      unsafeAtomicAdd(sxa + rv1, dot4(powr1, rab4));
      if (has3) unsafeAtomicAdd(sxa + rv2, dot4(powr2, rab4));
      ((float4*)s_cbv)[wl] = cv0;
      ((float4*)s_cbv)[wl + 448] = cv1;
      if (wl < 384) ((float4*)s_cbv)[wl + 896] = cv2;
    }
    gbar_arrive(bar, ++bgen, blk, tid);
    ++fgen;
    // ===== window-SX(l): wave0 produces sx; workers prefetch C weights =====
    if (!work) {
      sweep(bar, bgen, lane);
      const float* sb = sxacc + p * 4096;
#pragma unroll
      for (int j = 0; j < 8; ++j) {
        int idx = lane * 16 + 2 * j;
        float ax = 0.f, ay = 0.f;
#pragma unroll
        for (int c = 0; c < 4; ++c) {
          float2 t2 = ld_c2(sb + c * N + idx);
          ax += t2.x;
          ay += t2.y;
        }
        float2 x2 = ((const float2*)s_vx)[lane * 8 + j];
        float2 o;
        o.x = x2.x + ax;
        o.y = x2.y + ay;
        ((float2*)s_sx)[lane * 8 + j] = o;
      }
      set_gen(&s_flag, fgen);
      if (lane < 16) st_c(facc + (1 - p) * 4096 + blk * 16 + lane, 0.f);
    } else {
      pfC(l);
      wait_gen(&s_flag, fgen);
    }

    // ================= C body =================
    float4 av0, av1, av2, av3;
    const bool ldav = (l + 1 < NLAYERS);
    if (work) {
      if (ldav) {
        av0 = *(const float4*)abaddr(wl, l + 1);
        av1 = *(const float4*)abaddr(wl + 448, l + 1);
        av2 = *(const float4*)abaddr(wl + 896, l + 1);
        if (wl < 192) av3 = *(const float4*)abaddr(wl + 1344, l + 1);
      }
      float4 x2q[4];
#pragma unroll
      for (int k = 0; k < 4; ++k) x2q[k] = ((const float4*)s_sx)[(k << 6) + lane];
      ln16(x2q, s_cbv, s_cbv + N, lane);
      if (blk == 5 && wid == 1) {
#pragma unroll
        for (int k = 0; k < 4; ++k) ((float4*)sto)[(k << 6) + lane] = x2q[k];
      }
      float4 mk4[4], mr4[4];
#pragma unroll
      for (int k = 0; k < 4; ++k) {
        float4 s0 = ((const float4*)(s_cbv + 4 * N))[(k << 6) + lane];
        mk4[k] = mix4(x2q[k], s0, ((const float4*)(s_cbv + 2 * N))[(k << 6) + lane]);
        mr4[k] = mix4(x2q[k], s0, ((const float4*)(s_cbv + 3 * N))[(k << 6) + lane]);
      }
      float dA = 0.f, dB = 0.f, dC = 0.f;
#pragma unroll
      for (int k = 0; k < 4; ++k) {
        dA += dot4(pkA[k], (iA < 16) ? mk4[k] : mr4[k]);
        dB += dot4(pkB[k], (iB < 16) ? mk4[k] : mr4[k]);
        if (hasC) dC += dot4(pkC[k], (iC < 16) ? mk4[k] : mr4[k]);
      }
      dA = wred(dA);
      dB = wred(dB);
      if (hasC) dC = wred(dC);
      if (lane == 0) {
        if (iA < 16) { float t = fmaxf(dA, 0.f); s_kk[iA] = t * t; }
        else st_c(r2buf + (blk << 2) + (iA - 16), sigmoidf(dA));
        if (iB < 16) { float t = fmaxf(dB, 0.f); s_kk[iB] = t * t; }
        else st_c(r2buf + (blk << 2) + (iB - 16), sigmoidf(dB));
        if (hasC) {
          if (iC < 16) { float t = fmaxf(dC, 0.f); s_kk[iC] = t * t; }
          else st_c(r2buf + (blk << 2) + (iC - 16), sigmoidf(dC));
        }
      }
    }
    lbar();
    if (work) {
      float4 K0 = ((const float4*)s_kk)[0];
      float4 K1 = ((const float4*)s_kk)[1];
      float4 K2 = ((const float4*)s_kk)[2];
      float4 K3 = ((const float4*)s_kk)[3];
      float* fc = facc + p * 4096 + (blk & 3) * N;
      unsafeAtomicAdd(fc + rv0, dot4(pf0[0], K0) + dot4(pf0[1], K1) +
                                    dot4(pf0[2], K2) + dot4(pf0[3], K3));
      unsafeAtomicAdd(fc + rv1, dot4(pf1[0], K0) + dot4(pf1[1], K1) +
                                    dot4(pf1[2], K2) + dot4(pf1[3], K3));
      if (has3)
        unsafeAtomicAdd(fc + rv2, dot4(pf2[0], K0) + dot4(pf2[1], K1) +
                                      dot4(pf2[2], K2) + dot4(pf2[3], K3));
      if (ldav) {
        ((float4*)s_abv)[wl] = av0;
        ((float4*)s_abv)[wl + 448] = av1;
        ((float4*)s_abv)[wl + 896] = av2;
        if (wl < 192) ((float4*)s_abv)[wl + 1344] = av3;
      }
    }
    gbar_arrive(bar, ++bgen, blk, tid);
    ++fgen;
    // ===== window-X(l+1): wave0 produces x (or final xf); workers prefetch AB =====
    if (!work) {
      sweep(bar, bgen, lane);
      const float* fb = facc + p * 4096;
#pragma unroll
      for (int j = 0; j < 8; ++j) {
        int idx = lane * 16 + 2 * j;
        float ax = 0.f, ay = 0.f;
#pragma unroll
        for (int c = 0; c < 4; ++c) {
          float2 t2 = ld_c2(fb + c * N + idx);
          ax += t2.x;
          ay += t2.y;
        }
        float2 r2 = ld_c2(r2buf + idx);
        float2 sx2 = ((const float2*)s_sx)[lane * 8 + j];
        float2 o;
        o.x = sx2.x + r2.x * ax;
        o.y = sx2.y + r2.y * ay;
        ((float2*)s_vx)[lane * 8 + j] = o;
      }
      set_gen(&s_flag, fgen);
      if (ldav) {
        if (lane < 16) st_c(sxacc + p * 4096 + blk * 16 + lane, 0.f);
        if (lane < 4) {
          const float* stn = state + (size_t)(l + 1) * 5 * N;
          int ii = c0 + lane;
          kaa = stn[2 * N + ii];
          kbb = stn[3 * N + ii];
          kpp = stn[4 * N + ii];
          ktf = tf[(l + 1) * N + ii];
          ktd = td[(l + 1) * N + ii];
        }
      }
    } else {
      if (ldav) pfA(l + 1);
      wait_gen(&s_flag, fgen);
    }
  }

  // ================= head: logits = head @ LN(s_vx) =================
  {
    float4 xf[4];
#pragma unroll
    for (int k = 0; k < 4; ++k) xf[k] = ((const float4*)s_vx)[(k << 6) + lane];
    ln16(xf, lnoutw, lnoutb, lane);
    for (int base = (blk * 8 + wid) * 4; base < VOCAB; base += GRID * 8 * 4) {
      float4 h[4][4];
#pragma unroll
      for (int rr = 0; rr < 4; ++rr) {
        int row = base + rr;
        if (row < VOCAB) {
          const float4* hp = (const float4*)(head + (size_t)row * N);
#pragma unroll
          for (int k = 0; k < 4; ++k) h[rr][k] = hp[(k << 6) + lane];
        }
      }
#pragma unroll
      for (int rr = 0; rr < 4; ++rr) {
        int row = base + rr;
        if (row < VOCAB) {
          float d = 0.f;
#pragma unroll
          for (int k = 0; k < 4; ++k) d += dot4(h[rr][k], xf[k]);
          d = wred(d);
          if (lane == 0) logits[row] = d;
        }
      }
    }
  }
}

extern "C" void kernel_launch(void* const* d_in, const int* in_sizes, int n_in,
                              void* d_out, int out_size, void* d_ws, size_t ws_size,
                              hipStream_t stream) {
  const int* ctx = (const int*)d_in[0];
  const float* state = (const float*)d_in[1];
  const float* emb = (const float*)d_in[2];
  const float* ln0w = (const float*)d_in[3];
  const float* ln0b = (const float*)d_in[4];
  const float* ln1w = (const float*)d_in[5];
  const float* ln1b = (const float*)d_in[6];
  const float* amk = (const float*)d_in[7];
  const float* amv = (const float*)d_in[8];
  const float* amr = (const float*)d_in[9];
  const float* tf = (const float*)d_in[10];
  const float* td = (const float*)d_in[11];
  const float* kw = (const float*)d_in[12];
  const float* vw = (const float*)d_in[13];
  const float* rw = (const float*)d_in[14];
  const float* ow = (const float*)d_in[15];
  const float* ln2w = (const float*)d_in[16];
  const float* ln2b = (const float*)d_in[17];
  const float* fmk = (const float*)d_in[18];
  const float* fmr = (const float*)d_in[19];
  const float* fkw = (const float*)d_in[20];
  const float* fvw = (const float*)d_in[21];
  const float* frw = (const float*)d_in[22];
  const float* lnoutw = (const float*)d_in[23];
  const float* lnoutb = (const float*)d_in[24];
  const float* head = (const float*)d_in[25];
  float* out = (float*)d_out;
  float* ws = (float*)d_ws;
  unsigned* bar = (unsigned*)((char*)d_ws + BAR_OFF_BYTES);

  hipMemsetAsync(d_ws, 0, WS_CLEAR_BYTES, stream);

  void* args[] = {&ctx, &state, &emb, &ln0w, &ln0b, &ln1w, &ln1b,
                  &amk, &amv, &amr, &tf, &td, &kw, &vw, &rw, &ow,
                  &ln2w, &ln2b, &fmk, &fmr, &fkw, &fvw, &frw,
                  &lnoutw, &lnoutb, &head, &out, &ws, &bar};
  hipLaunchCooperativeKernel((const void*)k_rwkv, dim3(GRID), dim3(BLOCK),
                             args, 0, stream);
}